// Round 1
// baseline (1170.095 us; speedup 1.0000x reference)
//
#include <hip/hip_runtime.h>
#include <hip/hip_bf16.h>

// SNN forward: out[b,o] = mean_t v_out
// Structure:
//   prep:      w_rec [512,512] -> w_recT; w_out [20,512] -> w_outT
//   gemm_iff:  i_ff[t,b,h] = sum_c x[b,t,c] * w1[h,c]   (f32, 64x64 tiles)
//   snn_recur: fused 250-step recurrence, 1 wave per batch row, state in regs,
//              spikes exchanged via 64-lane ballot, sparse recurrent gather.

#define B_    256
#define T_    250
#define NIN   700
#define NHID  512
#define NOUT  20

// ---------------- prep: transposes ----------------
__global__ __launch_bounds__(256) void prep_kernel(
    const float* __restrict__ wrec, const float* __restrict__ wout,
    float* __restrict__ wrecT, float* __restrict__ woutT) {
  int i = blockIdx.x * 256 + threadIdx.x;
  if (i < NHID * NHID) {
    int h = i >> 9, hp = i & 511;          // wrec[h][hp]
    wrecT[hp * NHID + h] = wrec[i];
  }
  if (i < NOUT * NHID) {
    int o = i >> 9, hp = i & 511;          // wout[o][hp]
    woutT[hp * NOUT + o] = wout[i];
  }
}

// ---------------- f32 GEMM: i_ff ----------------
// out[m*512 + h], m = tl*256 + b  (tl = t - t0), A row = x[b][t0+tl][:]
#define BK 16
__global__ __launch_bounds__(256) void gemm_iff(
    const float* __restrict__ x, const float* __restrict__ w1,
    float* __restrict__ iff, int t0) {
  __shared__ __align__(16) float As[BK][68];
  __shared__ __align__(16) float Bs[BK][68];
  int h0 = blockIdx.x * 64;          // 8 h-tiles (fast dim -> L2 reuse of x tile)
  int m0 = blockIdx.y * 64;          // m-tiles
  int tid = threadIdx.x;
  int lrow = tid >> 2;               // 0..63
  int lc   = (tid & 3) * 4;          // 0,4,8,12
  int tm0  = (tid >> 4) * 4;         // 0..60
  int tn0  = (tid & 15) * 4;         // 0..60

  int m  = m0 + lrow;
  int tl = m >> 8;
  int b  = m & 255;
  const float* arow = x + ((size_t)b * T_ + (t0 + tl)) * NIN;
  const float* brow = w1 + (size_t)(h0 + lrow) * NIN;

  float acc[4][4] = {};

  for (int k0 = 0; k0 < NIN; k0 += BK) {
#pragma unroll
    for (int j = 0; j < 4; ++j) {
      int c = k0 + lc + j;
      float av = (c < NIN) ? arow[c] : 0.0f;
      float bv = (c < NIN) ? brow[c] : 0.0f;
      As[lc + j][lrow] = av;
      Bs[lc + j][lrow] = bv;
    }
    __syncthreads();
#pragma unroll
    for (int kk = 0; kk < BK; ++kk) {
      const float4 av = *(const float4*)&As[kk][tm0];
      const float4 bv = *(const float4*)&Bs[kk][tn0];
      acc[0][0] += av.x * bv.x; acc[0][1] += av.x * bv.y;
      acc[0][2] += av.x * bv.z; acc[0][3] += av.x * bv.w;
      acc[1][0] += av.y * bv.x; acc[1][1] += av.y * bv.y;
      acc[1][2] += av.y * bv.z; acc[1][3] += av.y * bv.w;
      acc[2][0] += av.z * bv.x; acc[2][1] += av.z * bv.y;
      acc[2][2] += av.z * bv.z; acc[2][3] += av.z * bv.w;
      acc[3][0] += av.w * bv.x; acc[3][1] += av.w * bv.y;
      acc[3][2] += av.w * bv.z; acc[3][3] += av.w * bv.w;
    }
    __syncthreads();
  }
#pragma unroll
  for (int i = 0; i < 4; ++i) {
    float4 v;
    v.x = acc[i][0]; v.y = acc[i][1]; v.z = acc[i][2]; v.w = acc[i][3];
    *(float4*)&iff[(size_t)(m0 + tm0 + i) * NHID + h0 + tn0] = v;
  }
}

// ---------------- fused recurrence ----------------
// 64 blocks x 256 threads; wave w handles batch row b = blk*4 + w.
// Lane owns 8 consecutive hidden units h = lane*8 .. lane*8+7.
// Spike masks: mask[r] bit l  <->  h = l*8 + r.
__global__ __launch_bounds__(256) void snn_recur(
    const float* __restrict__ iff, const float* __restrict__ wrecT,
    const float* __restrict__ woutT,
    const float* __restrict__ alpha, const float* __restrict__ rho,
    const float* __restrict__ beta_a, const float* __restrict__ beta_out,
    float* __restrict__ state, float* __restrict__ dout,
    int t0, int Tc, int first, int last) {
  __shared__ float wout_s[NHID * NOUT];  // 40 KB
  int tid = threadIdx.x;
  for (int i = tid; i < NHID * NOUT; i += 256) wout_s[i] = woutT[i];
  __syncthreads();

  int wave = tid >> 6;
  int lane = tid & 63;
  int b = blockIdx.x * 4 + wave;
  int hbase = lane * 8;

  float* v1s = state;                         // 256*512
  float* a1s = state + B_ * NHID;
  float* sps = state + 2 * B_ * NHID;
  float* vos = state + 3 * B_ * NHID;         // 256*20
  float* oss = vos + B_ * NOUT;

  float v1[8], a1[8], sp[8], al[8], rh[8], ba[8];
#pragma unroll
  for (int r = 0; r < 8; ++r) {
    int h = hbase + r;
    al[r] = alpha[h]; rh[r] = rho[h]; ba[r] = beta_a[h];
    if (first) { v1[r] = 0.f; a1[r] = 0.f; sp[r] = 0.f; }
    else {
      v1[r] = v1s[(size_t)b * NHID + h];
      a1[r] = a1s[(size_t)b * NHID + h];
      sp[r] = sps[(size_t)b * NHID + h];
    }
  }
  float vout = 0.f, osum = 0.f, bo = 0.f;
  if (lane < NOUT) {
    bo = beta_out[lane];
    if (!first) { vout = vos[b * NOUT + lane]; osum = oss[b * NOUT + lane]; }
  }

  unsigned long long mask[8];
#pragma unroll
  for (int r = 0; r < 8; ++r) mask[r] = __ballot(sp[r] != 0.f);

  // prefetch step 0
  size_t base0 = ((size_t)0 * B_ + b) * NHID + hbase;
  float4 c0 = *(const float4*)(iff + base0);
  float4 c1 = *(const float4*)(iff + base0 + 4);

  for (int tl = 0; tl < Tc; ++tl) {
    int nt = (tl + 1 < Tc) ? tl + 1 : tl;
    size_t nb = ((size_t)nt * B_ + b) * NHID + hbase;
    float4 n0 = *(const float4*)(iff + nb);
    float4 n1 = *(const float4*)(iff + nb + 4);

    float iv[8];
    iv[0] = c0.x; iv[1] = c0.y; iv[2] = c0.z; iv[3] = c0.w;
    iv[4] = c1.x; iv[5] = c1.y; iv[6] = c1.z; iv[7] = c1.w;

    // recurrent input from PREVIOUS spikes (sparse gather of w_recT rows)
    unsigned long long anyp = mask[0] | mask[1] | mask[2] | mask[3] |
                              mask[4] | mask[5] | mask[6] | mask[7];
    if (anyp) {
#pragma unroll
      for (int r2 = 0; r2 < 8; ++r2) {
        unsigned long long mm = mask[r2];
        while (mm) {
          int l2 = __ffsll(mm) - 1; mm &= (mm - 1);
          int hp = l2 * 8 + r2;
          const float* wr = wrecT + (size_t)hp * NHID + hbase;
          float4 w0 = *(const float4*)wr;
          float4 w1v = *(const float4*)(wr + 4);
          iv[0] += w0.x; iv[1] += w0.y; iv[2] += w0.z; iv[3] += w0.w;
          iv[4] += w1v.x; iv[5] += w1v.y; iv[6] += w1v.z; iv[7] += w1v.w;
        }
      }
    }

    // LIF update + spike + reset (order matches reference)
#pragma unroll
    for (int r = 0; r < 8; ++r) {
      a1[r] = rh[r] * a1[r] + ba[r] * sp[r];
      v1[r] = al[r] * v1[r] + (1.0f - al[r]) * iv[r] - a1[r];
      float s = (v1[r] - 1.0f > 0.0f) ? 1.0f : 0.0f;
      v1[r] -= s;            // reset by subtraction, THRESHOLD=1
      sp[r] = s;
      mask[r] = __ballot(s != 0.f);
    }

    // readout from CURRENT spikes
    unsigned long long anyc = mask[0] | mask[1] | mask[2] | mask[3] |
                              mask[4] | mask[5] | mask[6] | mask[7];
    if (lane < NOUT) {
      float io = 0.f;
      if (anyc) {
#pragma unroll
        for (int r2 = 0; r2 < 8; ++r2) {
          unsigned long long mm = mask[r2];
          while (mm) {
            int l2 = __ffsll(mm) - 1; mm &= (mm - 1);
            int hp = l2 * 8 + r2;
            io += wout_s[hp * NOUT + lane];
          }
        }
      }
      vout = bo * vout + (1.0f - bo) * io;
      float so = (vout - 1.0f > 0.0f) ? 1.0f : 0.0f;
      vout -= so;
      osum += vout;
    }
    c0 = n0; c1 = n1;
  }

  if (last) {
    if (lane < NOUT) dout[b * NOUT + lane] = osum / (float)T_;
  } else {
#pragma unroll
    for (int r = 0; r < 8; ++r) {
      int h = hbase + r;
      v1s[(size_t)b * NHID + h] = v1[r];
      a1s[(size_t)b * NHID + h] = a1[r];
      sps[(size_t)b * NHID + h] = sp[r];
    }
    if (lane < NOUT) { vos[b * NOUT + lane] = vout; oss[b * NOUT + lane] = osum; }
  }
}

extern "C" void kernel_launch(void* const* d_in, const int* in_sizes, int n_in,
                              void* d_out, int out_size, void* d_ws, size_t ws_size,
                              hipStream_t stream) {
  const float* x      = (const float*)d_in[0];
  const float* w1     = (const float*)d_in[1];
  const float* wrec   = (const float*)d_in[2];
  const float* wout   = (const float*)d_in[3];
  const float* alpha  = (const float*)d_in[4];
  const float* rho    = (const float*)d_in[5];
  const float* beta_a = (const float*)d_in[6];
  const float* bout   = (const float*)d_in[7];
  float* out = (float*)d_out;

  char* ws = (char*)d_ws;
  const size_t wrecT_off = 0;
  const size_t woutT_off = wrecT_off + (size_t)NHID * NHID * 4;          // 1 MB
  const size_t state_off = woutT_off + (size_t)NHID * NOUT * 4;          // +40 KB
  const size_t state_bytes = (size_t)(3 * B_ * NHID + 2 * B_ * NOUT) * 4;
  const size_t iff_off = state_off + state_bytes;

  float* wrecT = (float*)(ws + wrecT_off);
  float* woutT = (float*)(ws + woutT_off);
  float* statep = (float*)(ws + state_off);
  float* iff   = (float*)(ws + iff_off);

  const size_t per_step = (size_t)B_ * NHID * 4;  // 512 KB per timestep
  long long avail = (long long)ws_size - (long long)iff_off;
  int Tc = (int)(avail / (long long)per_step);
  if (Tc > T_) Tc = T_;
  if (Tc < 1) Tc = 1;  // hope ws is big enough; typical harness ws >> this

  prep_kernel<<<dim3((NHID * NHID + 255) / 256), dim3(256), 0, stream>>>(
      wrec, wout, wrecT, woutT);

  for (int t0 = 0; t0 < T_; t0 += Tc) {
    int tc = (T_ - t0 < Tc) ? (T_ - t0) : Tc;
    dim3 g(8, tc * 4);  // x = h-tiles (fast -> x-tile reuse), y = m-tiles
    gemm_iff<<<g, dim3(256), 0, stream>>>(x, w1, iff, t0);
    snn_recur<<<dim3(64), dim3(256), 0, stream>>>(
        iff, wrecT, woutT, alpha, rho, beta_a, bout, statep, out,
        t0, tc, (t0 == 0) ? 1 : 0, (t0 + tc >= T_) ? 1 : 0);
  }
}

// Round 2
// 232.995 us; speedup vs baseline: 5.0220x; 5.0220x over previous
//
#include <hip/hip_runtime.h>
#include <hip/hip_bf16.h>

// SNN forward, round 2: bf16 MFMA for i_ff.
//   prep:      w1 [512,700] f32 -> w1b [512,704] bf16 (zero-padded K)
//   gemm_mfma: iff[tl*256+b][h] (bf16) = x[b][t0+tl][:] . w1[h][:]
//              128x128 tile, BK=32, 4 waves, mfma_f32_16x16x32_bf16,
//              reg-staged A (f32->bf16 in flight), T2 XOR-swizzled LDS.
//   snn_recur: 256 blocks x 1 wave (1 block/CU), 8 h/lane, depth-8 static
//              prefetch ring, ballot spike masks, sparse gather fallback.

#define B_    256
#define T_    250
#define NIN   700
#define KPAD  704
#define NHID  512
#define NOUT  20

typedef __attribute__((ext_vector_type(8))) short short8;
typedef __attribute__((ext_vector_type(4))) float f32x4;

static __device__ __forceinline__ ushort f2bf(float f) {
  union { float f; unsigned u; } v; v.f = f;
  unsigned r = (v.u + 0x7FFF + ((v.u >> 16) & 1)) >> 16;  // RNE
  return (ushort)r;
}
static __device__ __forceinline__ float bf2f(ushort u) {
  union { unsigned u; float f; } v; v.u = ((unsigned)u) << 16;
  return v.f;
}

// ---------------- prep: w1 -> bf16 padded ----------------
__global__ __launch_bounds__(256) void prep_kernel(
    const float* __restrict__ w1, ushort* __restrict__ w1b) {
  int i = blockIdx.x * 256 + threadIdx.x;
  if (i >= NHID * KPAD) return;
  int h = i / KPAD, k = i - h * KPAD;
  w1b[i] = (k < NIN) ? f2bf(w1[(size_t)h * NIN + k]) : (ushort)0;
}

// ---------------- MFMA GEMM ----------------
// grid = (4, Tc*2); block = 256 (4 waves, 2x2 wave grid of 64x64)
__global__ __launch_bounds__(256) void gemm_mfma(
    const float* __restrict__ x, const ushort* __restrict__ w1b,
    ushort* __restrict__ iff, int t0) {
  __shared__ __align__(16) ushort As[128 * 32];  // 8 KB, swizzled
  __shared__ __align__(16) ushort Bs[128 * 32];  // 8 KB, swizzled

  int tid  = threadIdx.x;
  int lane = tid & 63;
  int wave = tid >> 6;
  int wr = wave >> 1, wc = wave & 1;
  int n0 = blockIdx.x * 128;
  int m0 = blockIdx.y * 128;
  int t  = t0 + (m0 >> 8);
  int b0 = m0 & 255;

  // staging: row/col sr = tid>>1 (0..127), k-offset sk = 0 or 16
  int sr = tid >> 1;
  int sk = (tid & 1) * 16;
  const float*  ap = x + ((size_t)(b0 + sr) * T_ + t) * NIN;
  const ushort* bp = w1b + (size_t)(n0 + sr) * KPAD + sk;

  int wby = sr * 64 + sk * 2;
  int swz = (sr & 7) << 4;
  int wb0 = (wby)      ^ swz;
  int wb1 = (wby + 16) ^ swz;

  f32x4 acc[4][4];
#pragma unroll
  for (int i = 0; i < 4; ++i)
#pragma unroll
    for (int j = 0; j < 4; ++j) acc[i][j] = (f32x4){0.f, 0.f, 0.f, 0.f};

  float4 ra[4];
  uint4 rb0, rb1;

  // load k-tile 0
  {
#pragma unroll
    for (int j = 0; j < 4; ++j) {
      int k = sk + j * 4;
      float4 v;
      if (k + 4 <= NIN) v = *(const float4*)(ap + k);
      else {
        v.x = (k + 0 < NIN) ? ap[k + 0] : 0.f;
        v.y = (k + 1 < NIN) ? ap[k + 1] : 0.f;
        v.z = (k + 2 < NIN) ? ap[k + 2] : 0.f;
        v.w = (k + 3 < NIN) ? ap[k + 3] : 0.f;
      }
      ra[j] = v;
    }
    rb0 = *(const uint4*)(bp);
    rb1 = *(const uint4*)(bp + 8);
  }

  const int NKT = KPAD / 32;  // 22
  for (int kt = 0; kt < NKT; ++kt) {
    __syncthreads();  // previous tile's reads complete
    // write staged regs to LDS (bf16, swizzled)
    {
      union { ushort s[8]; uint4 v; } u0, u1;
#pragma unroll
      for (int j = 0; j < 4; ++j) {
        u0.s[j * 2 + 0] = f2bf(ra[j].x);  // careful: keep k order
        u0.s[j * 2 + 1] = f2bf(ra[j].y);
        u1.s[j * 2 + 0] = f2bf(ra[j].z);
        u1.s[j * 2 + 1] = f2bf(ra[j].w);
      }
      // reorder: u0/u1 above interleave wrong; rebuild linearly
      union { ushort s[16]; uint4 v[2]; } lin;
#pragma unroll
      for (int j = 0; j < 4; ++j) {
        lin.s[j * 4 + 0] = f2bf(ra[j].x);
        lin.s[j * 4 + 1] = f2bf(ra[j].y);
        lin.s[j * 4 + 2] = f2bf(ra[j].z);
        lin.s[j * 4 + 3] = f2bf(ra[j].w);
      }
      *(uint4*)((char*)As + wb0) = lin.v[0];
      *(uint4*)((char*)As + wb1) = lin.v[1];
      *(uint4*)((char*)Bs + wb0) = rb0;
      *(uint4*)((char*)Bs + wb1) = rb1;
    }
    __syncthreads();

    // prefetch next k-tile (hides under MFMA)
    if (kt + 1 < NKT) {
      int k0 = (kt + 1) * 32;
#pragma unroll
      for (int j = 0; j < 4; ++j) {
        int k = k0 + sk + j * 4;
        float4 v;
        if (k + 4 <= NIN) v = *(const float4*)(ap + k);
        else {
          v.x = (k + 0 < NIN) ? ap[k + 0] : 0.f;
          v.y = (k + 1 < NIN) ? ap[k + 1] : 0.f;
          v.z = (k + 2 < NIN) ? ap[k + 2] : 0.f;
          v.w = (k + 3 < NIN) ? ap[k + 3] : 0.f;
        }
        ra[j] = v;
      }
      rb0 = *(const uint4*)(bp + (size_t)k0);
      rb1 = *(const uint4*)(bp + (size_t)k0 + 8);
    }

    // fragments + MFMA
    short8 af[4], bfr[4];
    int kg = (lane >> 4) * 16;        // 16B k-group offset
    int lswz = (lane & 7) << 4;
#pragma unroll
    for (int i = 0; i < 4; ++i) {
      int arow = wr * 64 + i * 16 + (lane & 15);
      af[i] = *(short8*)((char*)As + ((arow * 64 + kg) ^ lswz));
      int bcol = wc * 64 + i * 16 + (lane & 15);
      bfr[i] = *(short8*)((char*)Bs + ((bcol * 64 + kg) ^ lswz));
    }
#pragma unroll
    for (int i = 0; i < 4; ++i)
#pragma unroll
      for (int j = 0; j < 4; ++j)
        acc[i][j] = __builtin_amdgcn_mfma_f32_16x16x32_bf16(
            af[i], bfr[j], acc[i][j], 0, 0, 0);
  }

  // epilogue: C/D layout col=lane&15, row=(lane>>4)*4+reg  [m89/m91]
#pragma unroll
  for (int i = 0; i < 4; ++i) {
#pragma unroll
    for (int j = 0; j < 4; ++j) {
#pragma unroll
      for (int r = 0; r < 4; ++r) {
        int row = m0 + wr * 64 + i * 16 + (lane >> 4) * 4 + r;
        int col = n0 + wc * 64 + j * 16 + (lane & 15);
        iff[(size_t)row * NHID + col] = f2bf(acc[i][j][r]);
      }
    }
  }
}

// ---------------- fused recurrence ----------------
// 256 blocks x 64 threads; block b handles batch row b. Lane owns 8 h.
__global__ __launch_bounds__(64) void snn_recur(
    const ushort* __restrict__ iff, const float* __restrict__ wrec,
    const float* __restrict__ wout,
    const float* __restrict__ alpha, const float* __restrict__ rho,
    const float* __restrict__ beta_a, const float* __restrict__ beta_out,
    float* __restrict__ state, float* __restrict__ dout,
    int Tc, int first, int last) {
  int lane = threadIdx.x;
  int b = blockIdx.x;
  int hbase = lane * 8;

  float* v1s = state;
  float* a1s = state + B_ * NHID;
  float* sps = state + 2 * B_ * NHID;
  float* vos = state + 3 * B_ * NHID;
  float* oss = vos + B_ * NOUT;

  float v1[8], a1[8], sp[8], al[8], rh[8], ba[8];
#pragma unroll
  for (int r = 0; r < 8; ++r) {
    int h = hbase + r;
    al[r] = alpha[h]; rh[r] = rho[h]; ba[r] = beta_a[h];
    if (first) { v1[r] = 0.f; a1[r] = 0.f; sp[r] = 0.f; }
    else {
      v1[r] = v1s[(size_t)b * NHID + h];
      a1[r] = a1s[(size_t)b * NHID + h];
      sp[r] = sps[(size_t)b * NHID + h];
    }
  }
  float vout = 0.f, osum = 0.f, bo = 0.f;
  if (lane < NOUT) {
    bo = beta_out[lane];
    if (!first) { vout = vos[b * NOUT + lane]; osum = oss[b * NOUT + lane]; }
  }

  unsigned long long mask[8];
#pragma unroll
  for (int r = 0; r < 8; ++r) mask[r] = __ballot(sp[r] != 0.f);

  // depth-8 prefetch ring, static indices only (rule #20)
  short8 pf[8];
#pragma unroll
  for (int j = 0; j < 8; ++j) {
    int tl = (j < Tc) ? j : (Tc - 1);
    pf[j] = *(const short8*)(iff + ((size_t)tl * B_ + b) * NHID + hbase);
  }

  for (int tb = 0; tb < Tc; tb += 8) {
#pragma unroll
    for (int j = 0; j < 8; ++j) {
      int tl = tb + j;
      if (tl < Tc) {
        float iv[8];
#pragma unroll
        for (int r = 0; r < 8; ++r) iv[r] = bf2f((ushort)pf[j][r]);

        unsigned long long anyp = mask[0] | mask[1] | mask[2] | mask[3] |
                                  mask[4] | mask[5] | mask[6] | mask[7];
        if (anyp) {  // sparse recurrent gather (cold path)
#pragma unroll
          for (int r2 = 0; r2 < 8; ++r2) {
            unsigned long long mm = mask[r2];
            while (mm) {
              int l2 = __ffsll(mm) - 1; mm &= (mm - 1);
              int hp = l2 * 8 + r2;
#pragma unroll
              for (int r = 0; r < 8; ++r)
                iv[r] += wrec[(size_t)(hbase + r) * NHID + hp];
            }
          }
        }

#pragma unroll
        for (int r = 0; r < 8; ++r) {
          a1[r] = rh[r] * a1[r] + ba[r] * sp[r];
          v1[r] = al[r] * v1[r] + (1.0f - al[r]) * iv[r] - a1[r];
          float s = (v1[r] - 1.0f > 0.0f) ? 1.0f : 0.0f;
          v1[r] -= s;
          sp[r] = s;
          mask[r] = __ballot(s != 0.f);
        }

        unsigned long long anyc = mask[0] | mask[1] | mask[2] | mask[3] |
                                  mask[4] | mask[5] | mask[6] | mask[7];
        if (lane < NOUT) {
          float io = 0.f;
          if (anyc) {
#pragma unroll
            for (int r2 = 0; r2 < 8; ++r2) {
              unsigned long long mm = mask[r2];
              while (mm) {
                int l2 = __ffsll(mm) - 1; mm &= (mm - 1);
                int hp = l2 * 8 + r2;
                io += wout[(size_t)lane * NHID + hp];
              }
            }
          }
          vout = bo * vout + (1.0f - bo) * io;
          float so = (vout - 1.0f > 0.0f) ? 1.0f : 0.0f;
          vout -= so;
          osum += vout;
        }

        int nt = (tl + 8 < Tc) ? (tl + 8) : (Tc - 1);
        pf[j] = *(const short8*)(iff + ((size_t)nt * B_ + b) * NHID + hbase);
      }
    }
  }

  if (last) {
    if (lane < NOUT) dout[b * NOUT + lane] = osum / (float)T_;
  } else {
#pragma unroll
    for (int r = 0; r < 8; ++r) {
      int h = hbase + r;
      v1s[(size_t)b * NHID + h] = v1[r];
      a1s[(size_t)b * NHID + h] = a1[r];
      sps[(size_t)b * NHID + h] = sp[r];
    }
    if (lane < NOUT) { vos[b * NOUT + lane] = vout; oss[b * NOUT + lane] = osum; }
  }
}

extern "C" void kernel_launch(void* const* d_in, const int* in_sizes, int n_in,
                              void* d_out, int out_size, void* d_ws, size_t ws_size,
                              hipStream_t stream) {
  const float* x      = (const float*)d_in[0];
  const float* w1     = (const float*)d_in[1];
  const float* wrec   = (const float*)d_in[2];
  const float* wout   = (const float*)d_in[3];
  const float* alpha  = (const float*)d_in[4];
  const float* rho    = (const float*)d_in[5];
  const float* beta_a = (const float*)d_in[6];
  const float* bout   = (const float*)d_in[7];
  float* out = (float*)d_out;

  char* ws = (char*)d_ws;
  const size_t w1b_bytes = (size_t)NHID * KPAD * 2;                       // 704 KB
  const size_t state_off = w1b_bytes;                                     // 16-aligned
  const size_t state_bytes = (size_t)(3 * B_ * NHID + 2 * B_ * NOUT) * 4; // ~1.6 MB
  const size_t iff_off = state_off + state_bytes;

  ushort* w1b   = (ushort*)(ws);
  float*  statep = (float*)(ws + state_off);
  ushort* iff   = (ushort*)(ws + iff_off);

  const size_t per_step = (size_t)B_ * NHID * 2;  // 256 KB / timestep (bf16)
  long long avail = (long long)ws_size - (long long)iff_off;
  int Tc = (int)(avail / (long long)per_step);
  if (Tc > T_) Tc = T_;
  if (Tc < 1) Tc = 1;

  prep_kernel<<<dim3((NHID * KPAD + 255) / 256), dim3(256), 0, stream>>>(w1, w1b);

  for (int t0 = 0; t0 < T_; t0 += Tc) {
    int tc = (T_ - t0 < Tc) ? (T_ - t0) : Tc;
    gemm_mfma<<<dim3(4, tc * 2), dim3(256), 0, stream>>>(x, w1b, iff, t0);
    snn_recur<<<dim3(B_), dim3(64), 0, stream>>>(
        iff, wrec, wout, alpha, rho, beta_a, bout, statep, out,
        tc, (t0 == 0) ? 1 : 0, (t0 + tc >= T_) ? 1 : 0);
  }
}

// Round 3
// 150.919 us; speedup vs baseline: 7.7531x; 1.5438x over previous
//
#include <hip/hip_runtime.h>
#include <hip/hip_bf16.h>

// SNN forward, round 3.
//   prep:      w1 [512,700] f32 -> w1frag bf16 in per-lane MFMA fragment order
//              [kt][colblk][koct*16+colm][8]  (1KB-coalesced wave loads, no B LDS)
//   gemm_mfma: BM=128 x BN=512 (full N), 512 thr / 8 waves (2x4), grid=500.
//              A-only LDS (row stride 80B, conflict-free), double-buffered,
//              1 barrier per BK=32 k-tile, B frags straight from L2 to regs.
//   snn_recur: unchanged from R2 (1 wave per batch row, ballot spike masks).

#define B_    256
#define T_    250
#define NIN   700
#define KPAD  704
#define NKT   22          // KPAD/32
#define NHID  512
#define NOUT  20

typedef __attribute__((ext_vector_type(8))) short short8;
typedef __attribute__((ext_vector_type(4))) float f32x4;

static __device__ __forceinline__ ushort f2bf(float f) {
  union { float f; unsigned u; } v; v.f = f;
  unsigned r = (v.u + 0x7FFF + ((v.u >> 16) & 1)) >> 16;  // RNE
  return (ushort)r;
}
static __device__ __forceinline__ float bf2f(ushort u) {
  union { unsigned u; float f; } v; v.u = ((unsigned)u) << 16;
  return v.f;
}

// ---------------- prep: w1 -> bf16 fragment layout ----------------
// flat = ((kt*32 + colblk)*64 + (koct*16 + colm))*8 + e
//   maps to w1[col = colblk*16+colm][k = kt*32 + koct*8 + e], 0-padded k>=700
__global__ __launch_bounds__(256) void prep_kernel(
    const float* __restrict__ w1, ushort* __restrict__ w1frag) {
  int i = blockIdx.x * 256 + threadIdx.x;
  if (i >= NKT * 32 * 64 * 8) return;
  int e      = i & 7;
  int colm   = (i >> 3) & 15;
  int koct   = (i >> 7) & 3;
  int colblk = (i >> 9) & 31;
  int kt     = i >> 14;
  int k   = kt * 32 + koct * 8 + e;
  int col = colblk * 16 + colm;
  w1frag[i] = (k < NIN) ? f2bf(w1[(size_t)col * NIN + k]) : (ushort)0;
}

// ---------------- MFMA GEMM ----------------
__global__ __launch_bounds__(512, 2) void gemm_mfma(
    const float* __restrict__ x, const ushort* __restrict__ w1frag,
    ushort* __restrict__ iff, int t0) {
  __shared__ __align__(16) char Abuf[2][128 * 80];  // 80B row stride: bank-free

  int tid  = threadIdx.x;
  int lane = tid & 63;
  int wave = tid >> 6;
  int wr = wave >> 2;          // 0..1  (64-row group)
  int wc = wave & 3;           // 0..3  (128-col group)
  int blk = blockIdx.x;
  int m0 = blk * 128;
  int t  = t0 + (blk >> 1);
  int b0 = (blk & 1) * 128;

  // A staging: thread -> (row, k-quad)
  int srow = tid >> 2;         // 0..127
  int skq  = tid & 3;          // 8 f32 at k = kt*32 + skq*8
  const float* ap = x + ((size_t)(b0 + srow) * T_ + t) * NIN;
  int swb = srow * 80 + skq * 16;

  int lm = lane & 15, lk = lane >> 4;
  const ushort* bbase = w1frag + ((size_t)wc * 8 * 64 + lane) * 8;

  f32x4 acc[4][8];
#pragma unroll
  for (int i = 0; i < 4; ++i)
#pragma unroll
    for (int j = 0; j < 8; ++j) acc[i][j] = (f32x4){0.f, 0.f, 0.f, 0.f};

#define LOADA(d0, d1, KT) do {                                               \
    int k0_ = (KT) * 32 + skq * 8;                                           \
    if (k0_ + 8 <= NIN) {                                                    \
      d0 = *(const float4*)(ap + k0_); d1 = *(const float4*)(ap + k0_ + 4);  \
    } else if (k0_ + 4 <= NIN) {                                             \
      d0 = *(const float4*)(ap + k0_); d1 = (float4){0.f,0.f,0.f,0.f};       \
    } else { d0 = (float4){0.f,0.f,0.f,0.f}; d1 = (float4){0.f,0.f,0.f,0.f}; } \
  } while (0)

#define WRITEA(BUF, s0, s1) do {                                             \
    union { ushort s[8]; uint4 v; } pk_;                                     \
    pk_.s[0]=f2bf(s0.x); pk_.s[1]=f2bf(s0.y); pk_.s[2]=f2bf(s0.z); pk_.s[3]=f2bf(s0.w); \
    pk_.s[4]=f2bf(s1.x); pk_.s[5]=f2bf(s1.y); pk_.s[6]=f2bf(s1.z); pk_.s[7]=f2bf(s1.w); \
    *(uint4*)(&Abuf[BUF][swb]) = pk_.v;                                      \
  } while (0)

#define LOADB(dst, KT) do {                                                  \
    const ushort* bp_ = bbase + (size_t)(KT) * 16384;                        \
    _Pragma("unroll")                                                        \
    for (int j_ = 0; j_ < 8; ++j_) dst[j_] = *(const short8*)(bp_ + j_ * 512); \
  } while (0)

  float4 s0a, s1a, s0b, s1b;       // A stage ping-pong (slot kt&1 holds tile kt+1)
  short8 Bfr0[8], Bfr1[8];         // B frag ping-pong (slot kt&1 holds tile kt)

  // prologue: tile0 -> Abuf[0]; B tile0 -> Bfr0; A tile1 -> slot0
  {
    float4 p0, p1;
    LOADA(p0, p1, 0);
    LOADB(Bfr0, 0);
    LOADA(s0a, s1a, 1);
    WRITEA(0, p0, p1);
  }
  __syncthreads();

#pragma unroll 2
  for (int kt = 0; kt < NKT; ++kt) {
    const int cur = kt & 1;
    // issue next-next A stage (tile kt+2) into slot cur^1
    if (kt + 2 < NKT) {
      if (cur == 0) { LOADA(s0b, s1b, kt + 2); } else { LOADA(s0a, s1a, kt + 2); }
    }
    // issue next B frags (tile kt+1) into slot cur^1
    if (kt + 1 < NKT) {
      if (cur == 0) { LOADB(Bfr1, kt + 1); } else { LOADB(Bfr0, kt + 1); }
    }
    // A fragments from LDS
    short8 af[4];
#pragma unroll
    for (int i = 0; i < 4; ++i)
      af[i] = *(const short8*)(&Abuf[cur][(wr * 64 + i * 16 + lm) * 80 + lk * 16]);
    // 32 MFMA
#pragma unroll
    for (int i = 0; i < 4; ++i)
#pragma unroll
      for (int j = 0; j < 8; ++j)
        acc[i][j] = __builtin_amdgcn_mfma_f32_16x16x32_bf16(
            af[i], (cur == 0) ? Bfr0[j] : Bfr1[j], acc[i][j], 0, 0, 0);
    // write tile kt+1 (staged at kt-1) into Abuf[cur^1]; one barrier per tile
    if (kt + 1 < NKT) {
      if (cur == 0) { WRITEA(1, s0a, s1a); } else { WRITEA(0, s0b, s1b); }
      __syncthreads();
    }
  }
#undef LOADA
#undef WRITEA
#undef LOADB

  // epilogue: C/D layout col=lane&15, row=(lane>>4)*4+reg  [m89/m91]
#pragma unroll
  for (int i = 0; i < 4; ++i) {
#pragma unroll
    for (int r = 0; r < 4; ++r) {
      int row = m0 + wr * 64 + i * 16 + lk * 4 + r;
      ushort* op = iff + (size_t)row * NHID + wc * 128 + lm;
#pragma unroll
      for (int j = 0; j < 8; ++j) op[j * 16] = f2bf(acc[i][j][r]);
    }
  }
}

// ---------------- fused recurrence (unchanged from R2) ----------------
__global__ __launch_bounds__(64) void snn_recur(
    const ushort* __restrict__ iff, const float* __restrict__ wrec,
    const float* __restrict__ wout,
    const float* __restrict__ alpha, const float* __restrict__ rho,
    const float* __restrict__ beta_a, const float* __restrict__ beta_out,
    float* __restrict__ state, float* __restrict__ dout,
    int Tc, int first, int last) {
  int lane = threadIdx.x;
  int b = blockIdx.x;
  int hbase = lane * 8;

  float* v1s = state;
  float* a1s = state + B_ * NHID;
  float* sps = state + 2 * B_ * NHID;
  float* vos = state + 3 * B_ * NHID;
  float* oss = vos + B_ * NOUT;

  float v1[8], a1[8], sp[8], al[8], rh[8], ba[8];
#pragma unroll
  for (int r = 0; r < 8; ++r) {
    int h = hbase + r;
    al[r] = alpha[h]; rh[r] = rho[h]; ba[r] = beta_a[h];
    if (first) { v1[r] = 0.f; a1[r] = 0.f; sp[r] = 0.f; }
    else {
      v1[r] = v1s[(size_t)b * NHID + h];
      a1[r] = a1s[(size_t)b * NHID + h];
      sp[r] = sps[(size_t)b * NHID + h];
    }
  }
  float vout = 0.f, osum = 0.f, bo = 0.f;
  if (lane < NOUT) {
    bo = beta_out[lane];
    if (!first) { vout = vos[b * NOUT + lane]; osum = oss[b * NOUT + lane]; }
  }

  unsigned long long mask[8];
#pragma unroll
  for (int r = 0; r < 8; ++r) mask[r] = __ballot(sp[r] != 0.f);

  short8 pf[8];
#pragma unroll
  for (int j = 0; j < 8; ++j) {
    int tl = (j < Tc) ? j : (Tc - 1);
    pf[j] = *(const short8*)(iff + ((size_t)tl * B_ + b) * NHID + hbase);
  }

  for (int tb = 0; tb < Tc; tb += 8) {
#pragma unroll
    for (int j = 0; j < 8; ++j) {
      int tl = tb + j;
      if (tl < Tc) {
        float iv[8];
#pragma unroll
        for (int r = 0; r < 8; ++r) iv[r] = bf2f((ushort)pf[j][r]);

        unsigned long long anyp = mask[0] | mask[1] | mask[2] | mask[3] |
                                  mask[4] | mask[5] | mask[6] | mask[7];
        if (anyp) {
#pragma unroll
          for (int r2 = 0; r2 < 8; ++r2) {
            unsigned long long mm = mask[r2];
            while (mm) {
              int l2 = __ffsll(mm) - 1; mm &= (mm - 1);
              int hp = l2 * 8 + r2;
#pragma unroll
              for (int r = 0; r < 8; ++r)
                iv[r] += wrec[(size_t)(hbase + r) * NHID + hp];
            }
          }
        }

#pragma unroll
        for (int r = 0; r < 8; ++r) {
          a1[r] = rh[r] * a1[r] + ba[r] * sp[r];
          v1[r] = al[r] * v1[r] + (1.0f - al[r]) * iv[r] - a1[r];
          float s = (v1[r] - 1.0f > 0.0f) ? 1.0f : 0.0f;
          v1[r] -= s;
          sp[r] = s;
          mask[r] = __ballot(s != 0.f);
        }

        unsigned long long anyc = mask[0] | mask[1] | mask[2] | mask[3] |
                                  mask[4] | mask[5] | mask[6] | mask[7];
        if (lane < NOUT) {
          float io = 0.f;
          if (anyc) {
#pragma unroll
            for (int r2 = 0; r2 < 8; ++r2) {
              unsigned long long mm = mask[r2];
              while (mm) {
                int l2 = __ffsll(mm) - 1; mm &= (mm - 1);
                int hp = l2 * 8 + r2;
                io += wout[(size_t)lane * NHID + hp];
              }
            }
          }
          vout = bo * vout + (1.0f - bo) * io;
          float so = (vout - 1.0f > 0.0f) ? 1.0f : 0.0f;
          vout -= so;
          osum += vout;
        }

        int nt = (tl + 8 < Tc) ? (tl + 8) : (Tc - 1);
        pf[j] = *(const short8*)(iff + ((size_t)nt * B_ + b) * NHID + hbase);
      }
    }
  }

  if (last) {
    if (lane < NOUT) dout[b * NOUT + lane] = osum / (float)T_;
  } else {
#pragma unroll
    for (int r = 0; r < 8; ++r) {
      int h = hbase + r;
      v1s[(size_t)b * NHID + h] = v1[r];
      a1s[(size_t)b * NHID + h] = a1[r];
      sps[(size_t)b * NHID + h] = sp[r];
    }
    if (lane < NOUT) { vos[b * NOUT + lane] = vout; oss[b * NOUT + lane] = osum; }
  }
}

extern "C" void kernel_launch(void* const* d_in, const int* in_sizes, int n_in,
                              void* d_out, int out_size, void* d_ws, size_t ws_size,
                              hipStream_t stream) {
  const float* x      = (const float*)d_in[0];
  const float* w1     = (const float*)d_in[1];
  const float* wrec   = (const float*)d_in[2];
  const float* wout   = (const float*)d_in[3];
  const float* alpha  = (const float*)d_in[4];
  const float* rho    = (const float*)d_in[5];
  const float* beta_a = (const float*)d_in[6];
  const float* bout   = (const float*)d_in[7];
  float* out = (float*)d_out;

  char* ws = (char*)d_ws;
  const size_t w1frag_bytes = (size_t)NKT * 32 * 64 * 8 * 2;                 // 704 KB
  const size_t state_off = w1frag_bytes;
  const size_t state_bytes = (size_t)(3 * B_ * NHID + 2 * B_ * NOUT) * 4;    // ~1.6 MB
  const size_t iff_off = state_off + state_bytes;

  ushort* w1frag = (ushort*)(ws);
  float*  statep = (float*)(ws + state_off);
  ushort* iff    = (ushort*)(ws + iff_off);

  const size_t per_step = (size_t)B_ * NHID * 2;  // 256 KB per timestep (bf16)
  long long avail = (long long)ws_size - (long long)iff_off;
  int Tc = (int)(avail / (long long)per_step);
  if (Tc > T_) Tc = T_;
  if (Tc < 1) Tc = 1;

  prep_kernel<<<dim3((NKT * 32 * 64 * 8 + 255) / 256), dim3(256), 0, stream>>>(
      w1, w1frag);

  for (int t0 = 0; t0 < T_; t0 += Tc) {
    int tc = (T_ - t0 < Tc) ? (T_ - t0) : Tc;
    gemm_mfma<<<dim3(tc * 2), dim3(512), 0, stream>>>(x, w1frag, iff, t0);
    snn_recur<<<dim3(B_), dim3(64), 0, stream>>>(
        iff, wrec, wout, alpha, rho, beta_a, bout, statep, out,
        tc, (t0 == 0) ? 1 : 0, (t0 + tc >= T_) ? 1 : 0);
  }
}